// Round 4
// baseline (457.468 us; speedup 1.0000x reference)
//
#include <hip/hip_runtime.h>

// MoE EP-combine: out[idx[r]] += gates[r] * expert[r]   (fp32)
// Gather formulation: CSR-lite build in d_ws (counts + fixed-width slot
// lists), then 2 blocks per output token gather contributor half-rows,
// weight, sum, write once (no pre-zero of d_out: every element written).
//
// Round-3 A/B: REMOVE all nontemporal hints. History: 3 combine structures
// (2blk/token x1, x2-unroll, wave/token x8-burst) all ~108-116us of our time
// -> not MLP/granularity-bound. Decomposition: combine ~89us for 402MB
// (4.5 TB/s) while harness fillBuffer (plain writes) hits 6.5 TB/s in the
// same window. Hypothesis: nt-STORE path (~3 TB/s effective on 134MB writes)
// is the entire residual gap; reads already full-rate. No reuse exists, so
// nt's L2-protection buys nothing. Single-variable change vs round-2 source.

static constexpr int NT   = 256;  // threads per block
static constexpr int MAXK = 32;   // max contributors per token (Poisson(2) max ~13)

typedef float fvec4 __attribute__((ext_vector_type(4)));

__device__ __forceinline__ void fma4(fvec4& a, float g, fvec4 e) {
    a.x = fmaf(g, e.x, a.x);
    a.y = fmaf(g, e.y, a.y);
    a.z = fmaf(g, e.z, a.z);
    a.w = fmaf(g, e.w, a.w);
}

// Inline int64-layout detection: if the index buffer is int64 (little-endian),
// the high 32-bit words of the first 16 values are all zero (indices small,
// non-negative). For int32 data those words are 16 independent token indices —
// all-zero with probability ~16384^-16. Wave-uniform reads -> L1 broadcast.
__device__ __forceinline__ int detect_is64(const int* __restrict__ idx32) {
    int is64 = 1;
#pragma unroll
    for (int i = 1; i < 32; i += 2) is64 &= (idx32[i] == 0);
    return is64;
}

__global__ void fill_kernel(const int* __restrict__ idx32,
                            const long long* __restrict__ idx64,
                            int* __restrict__ counts,
                            int* __restrict__ slots,
                            int num_sel, int num_tokens) {
    int r = blockIdx.x * blockDim.x + threadIdx.x;
    if (r >= num_sel) return;
    int is64 = detect_is64(idx32);
    int t = is64 ? (int)idx64[r] : idx32[r];
    if ((unsigned)t >= (unsigned)num_tokens) return;  // safety net
    int j = atomicAdd(&counts[t], 1);
    if (j < MAXK) slots[t * MAXK + j] = r;
}

// Specialized for d_model == 2048: 2 blocks per token, 1 float4 per thread,
// contributor loop unrolled x2. Plain (cached) loads and stores: write path
// goes through L2 write-allocate like the 6.5 TB/s harness fills.
__global__ __launch_bounds__(NT) void combine2048_kernel(
    const float* __restrict__ expert,
    const float* __restrict__ gates,
    const int* __restrict__ counts,
    const int* __restrict__ slots,
    float* __restrict__ out) {
    const int b    = blockIdx.x;
    const int t    = b >> 1;                       // token
    const int col4 = ((b & 1) * NT + threadIdx.x); // float4 index in [0,512)
    int c = counts[t];
    if (c > MAXK) c = MAXK;
    const int* sl = slots + t * MAXK;

    fvec4 acc = (fvec4)(0.f);
    int j = 0;
    for (; j + 2 <= c; j += 2) {
        const int   r0 = sl[j];                    // wave-uniform (s_load)
        const int   r1 = sl[j + 1];
        const float g0 = gates[r0];                // wave-uniform
        const float g1 = gates[r1];
        const fvec4* R0 = (const fvec4*)(expert + (size_t)r0 * 2048);
        const fvec4* R1 = (const fvec4*)(expert + (size_t)r1 * 2048);
        fvec4 e0 = R0[col4];                       // plain cached load
        fvec4 e1 = R1[col4];
        fma4(acc, g0, e0);
        fma4(acc, g1, e1);
    }
    if (j < c) {
        const int   r = sl[j];
        const float g = gates[r];
        const fvec4* R = (const fvec4*)(expert + (size_t)r * 2048);
        fvec4 e = R[col4];
        fma4(acc, g, e);
    }
    fvec4* o = (fvec4*)(out + (size_t)t * 2048);
    o[col4] = acc;                                 // plain cached store
}

// Fallback: plain atomic scatter (generic d_model, or ws too small).
__global__ void scatter_atomic_kernel(const float* __restrict__ expert,
                                      const float* __restrict__ gates,
                                      const int* __restrict__ idx32,
                                      const long long* __restrict__ idx64,
                                      float* __restrict__ out,
                                      int d_model, int num_tokens) {
    int r = blockIdx.x;
    int is64 = detect_is64(idx32);
    int t = is64 ? (int)idx64[r] : idx32[r];
    if ((unsigned)t >= (unsigned)num_tokens) return;
    float g = gates[r];
    const float* row  = expert + (size_t)r * d_model;
    float*       orow = out    + (size_t)t * d_model;
    for (int v = threadIdx.x; v < d_model; v += blockDim.x)
        atomicAdd(&orow[v], g * row[v]);
}

extern "C" void kernel_launch(void* const* d_in, const int* in_sizes, int n_in,
                              void* d_out, int out_size, void* d_ws, size_t ws_size,
                              hipStream_t stream) {
    const float*      expert = (const float*)d_in[1];
    const float*      gates  = (const float*)d_in[2];
    const int*        idx32  = (const int*)d_in[3];
    const long long*  idx64  = (const long long*)d_in[3];
    float*            out    = (float*)d_out;

    const int num_sel    = in_sizes[2];
    const int d_model    = (int)((long long)in_sizes[1] / num_sel);
    const int num_tokens = (int)((long long)out_size / d_model);

    int*  counts = (int*)d_ws;
    int*  slots  = (int*)((char*)d_ws + (size_t)num_tokens * 4);
    const size_t need = (size_t)num_tokens * 4 + (size_t)num_tokens * MAXK * 4;

    if (d_model == 2048 && ws_size >= need) {
        (void)hipMemsetAsync(counts, 0, (size_t)num_tokens * 4, stream);
        fill_kernel<<<(num_sel + NT - 1) / NT, NT, 0, stream>>>(
            idx32, idx64, counts, slots, num_sel, num_tokens);
        combine2048_kernel<<<num_tokens * 2, NT, 0, stream>>>(expert, gates, counts, slots, out);
    } else {
        (void)hipMemsetAsync(d_out, 0, (size_t)out_size * sizeof(float), stream);
        scatter_atomic_kernel<<<num_sel, NT, 0, stream>>>(
            expert, gates, idx32, idx64, out, d_model, num_tokens);
    }
}

// Round 5
// 447.703 us; speedup vs baseline: 1.0218x; 1.0218x over previous
//
#include <hip/hip_runtime.h>

// MoE EP-combine: out[idx[r]] += gates[r] * expert[r]   (fp32)
// Gather formulation: CSR-lite build in d_ws (counts + fixed-width slot
// lists), then combine: 1 unit = (token, half-row); PERSISTENT grid of 2048
// blocks (8/CU co-resident) grid-strides over the 2*T units, so each wave
// stays alive and the per-unit CSR preamble (counts->slots->gates dependent
// L2 chain, ~800cy) pipelines behind the previous unit's expert loads/stores
// instead of being paid cold by a fresh block 32768 times.
//
// History: R1 proved the 2x1GiB 0xAA ws re-poison (~326us/iter) is
// UNCONDITIONAL. R2 (unroll2) neutral -> not MLP-starved. R3 (wave/token
// 8KB bursts) regressed -> not granularity-bound. R4 (plain loads/stores)
// regressed +21us -> nt load/store is optimal (single-use stream, keep it
// out of L2). Remaining lever = block churn; this round tests it.

static constexpr int NT   = 256;   // threads per block
static constexpr int MAXK = 32;    // max contributors per token (Poisson(2) max ~13)
static constexpr int PERSIST_BLOCKS = 2048;  // 8 blocks/CU x 256 CU co-resident

typedef float fvec4 __attribute__((ext_vector_type(4)));

__device__ __forceinline__ void fma4(fvec4& a, float g, fvec4 e) {
    a.x = fmaf(g, e.x, a.x);
    a.y = fmaf(g, e.y, a.y);
    a.z = fmaf(g, e.z, a.z);
    a.w = fmaf(g, e.w, a.w);
}

// Inline int64-layout detection: if the index buffer is int64 (little-endian),
// the high 32-bit words of the first 16 values are all zero (indices small,
// non-negative). For int32 data those words are 16 independent token indices —
// all-zero with probability ~16384^-16. Wave-uniform reads -> L1 broadcast.
__device__ __forceinline__ int detect_is64(const int* __restrict__ idx32) {
    int is64 = 1;
#pragma unroll
    for (int i = 1; i < 32; i += 2) is64 &= (idx32[i] == 0);
    return is64;
}

__global__ void fill_kernel(const int* __restrict__ idx32,
                            const long long* __restrict__ idx64,
                            int* __restrict__ counts,
                            int* __restrict__ slots,
                            int num_sel, int num_tokens) {
    int r = blockIdx.x * blockDim.x + threadIdx.x;
    if (r >= num_sel) return;
    int is64 = detect_is64(idx32);
    int t = is64 ? (int)idx64[r] : idx32[r];
    if ((unsigned)t >= (unsigned)num_tokens) return;  // safety net
    int j = atomicAdd(&counts[t], 1);
    if (j < MAXK) slots[t * MAXK + j] = r;
}

// d_model == 2048, persistent: unit b = (token b>>1, half b&1); each block
// handles units b, b+grid, b+2*grid, ... Body identical to the measured-best
// R0/R2 structure (nt loads/stores, unroll-2 contributor loop).
__global__ __launch_bounds__(NT, 8) void combine2048_persist_kernel(
    const float* __restrict__ expert,
    const float* __restrict__ gates,
    const int* __restrict__ counts,
    const int* __restrict__ slots,
    float* __restrict__ out,
    int nunits) {
    for (int b = blockIdx.x; b < nunits; b += gridDim.x) {
        const int t    = b >> 1;                       // token
        const int col4 = ((b & 1) * NT + threadIdx.x); // float4 index in [0,512)
        int c = counts[t];
        if (c > MAXK) c = MAXK;
        const int* sl = slots + (size_t)t * MAXK;

        fvec4 acc = (fvec4)(0.f);
        int j = 0;
        for (; j + 2 <= c; j += 2) {
            const int   r0 = sl[j];                    // wave-uniform
            const int   r1 = sl[j + 1];
            const float g0 = gates[r0];                // wave-uniform, L2-hot
            const float g1 = gates[r1];
            const fvec4* R0 = (const fvec4*)(expert + (size_t)r0 * 2048);
            const fvec4* R1 = (const fvec4*)(expert + (size_t)r1 * 2048);
            fvec4 e0 = __builtin_nontemporal_load(R0 + col4);  // streamed once
            fvec4 e1 = __builtin_nontemporal_load(R1 + col4);
            fma4(acc, g0, e0);
            fma4(acc, g1, e1);
        }
        if (j < c) {
            const int   r = sl[j];
            const float g = gates[r];
            const fvec4* R = (const fvec4*)(expert + (size_t)r * 2048);
            fvec4 e = __builtin_nontemporal_load(R + col4);
            fma4(acc, g, e);
        }
        fvec4* o = (fvec4*)(out + (size_t)t * 2048);
        __builtin_nontemporal_store(acc, o + col4);    // write-only: nt
    }
}

// Fallback: plain atomic scatter (generic d_model, or ws too small).
__global__ void scatter_atomic_kernel(const float* __restrict__ expert,
                                      const float* __restrict__ gates,
                                      const int* __restrict__ idx32,
                                      const long long* __restrict__ idx64,
                                      float* __restrict__ out,
                                      int d_model, int num_tokens) {
    int r = blockIdx.x;
    int is64 = detect_is64(idx32);
    int t = is64 ? (int)idx64[r] : idx32[r];
    if ((unsigned)t >= (unsigned)num_tokens) return;
    float g = gates[r];
    const float* row  = expert + (size_t)r * d_model;
    float*       orow = out    + (size_t)t * d_model;
    for (int v = threadIdx.x; v < d_model; v += blockDim.x)
        atomicAdd(&orow[v], g * row[v]);
}

extern "C" void kernel_launch(void* const* d_in, const int* in_sizes, int n_in,
                              void* d_out, int out_size, void* d_ws, size_t ws_size,
                              hipStream_t stream) {
    const float*      expert = (const float*)d_in[1];
    const float*      gates  = (const float*)d_in[2];
    const int*        idx32  = (const int*)d_in[3];
    const long long*  idx64  = (const long long*)d_in[3];
    float*            out    = (float*)d_out;

    const int num_sel    = in_sizes[2];
    const int d_model    = (int)((long long)in_sizes[1] / num_sel);
    const int num_tokens = (int)((long long)out_size / d_model);

    int*  counts = (int*)d_ws;
    int*  slots  = (int*)((char*)d_ws + (size_t)num_tokens * 4);
    const size_t need = (size_t)num_tokens * 4 + (size_t)num_tokens * MAXK * 4;

    if (d_model == 2048 && ws_size >= need) {
        (void)hipMemsetAsync(counts, 0, (size_t)num_tokens * 4, stream);
        fill_kernel<<<(num_sel + NT - 1) / NT, NT, 0, stream>>>(
            idx32, idx64, counts, slots, num_sel, num_tokens);
        const int nunits = num_tokens * 2;
        const int grid   = nunits < PERSIST_BLOCKS ? nunits : PERSIST_BLOCKS;
        combine2048_persist_kernel<<<grid, NT, 0, stream>>>(
            expert, gates, counts, slots, out, nunits);
    } else {
        (void)hipMemsetAsync(d_out, 0, (size_t)out_size * sizeof(float), stream);
        scatter_atomic_kernel<<<num_sel, NT, 0, stream>>>(
            expert, gates, idx32, idx64, out, d_model, num_tokens);
    }
}

// Round 6
// 436.428 us; speedup vs baseline: 1.0482x; 1.0258x over previous
//
#include <hip/hip_runtime.h>

// MoE EP-combine: out[idx[r]] += gates[r] * expert[r]   (fp32)
// Gather formulation: CSR-lite build (counts + fixed-width slot lists), then
// 2 blocks per output token gather contributor half-rows, weight, sum, write
// once (no pre-zero of d_out needed: every output element written).
//
// FINAL (revert to measured-best R0 structure). Falsification matrix over
// the combine stage (dur_us; fixed harness overhead ~347us of which ~326us
// is the UNCONDITIONAL 2x1GiB 0xAA ws re-poison, proven in R1):
//   R0 nt + 2blk/token           435.0   <- best (this kernel)
//   R2 +unroll2 (MLP depth)      436.7   neutral
//   R3 wave/token 8KB bursts     445.7   hurt
//   R4 plain cached ld/st        457.5   hurt (nt is right: single-use stream)
//   R5 persistent 8/CU grid      447.7   hurt
// Combine ~89us for 402MB (~4.5 TB/s) = floor for interleaved random-row
// gather + write + CSR metadata; harness's 6.5 TB/s is a pure-seq-write
// best case, not attainable here.

static constexpr int NT   = 256;  // threads per block
static constexpr int MAXK = 32;   // max contributors per token (Poisson(2) max ~10)

typedef float fvec4 __attribute__((ext_vector_type(4)));

// ws layout: [0 ..) counts[num_tokens] | slots[num_tokens*MAXK]

__global__ void fill_kernel(const int* __restrict__ idx32,
                            const long long* __restrict__ idx64,
                            int* __restrict__ counts,
                            int* __restrict__ slots,
                            int num_sel, int num_tokens) {
    int r = blockIdx.x * blockDim.x + threadIdx.x;
    if (r >= num_sel) return;
    // Inline int64-layout detection: if the buffer is int64 (little-endian),
    // the high 32-bit words of the first 16 values are all zero (indices are
    // small non-negative). For int32 data those words are 16 independent
    // token indices -- all-zero with probability ~16384^-16. Wave-uniform
    // reads of the same 128 B -> L1 broadcast, ~free.
    int is64 = 1;
#pragma unroll
    for (int i = 1; i < 32; i += 2) is64 &= (idx32[i] == 0);
    int t = is64 ? (int)idx64[r] : idx32[r];
    if ((unsigned)t >= (unsigned)num_tokens) return;  // safety net
    int j = atomicAdd(&counts[t], 1);
    if (j < MAXK) slots[t * MAXK + j] = r;
}

// Specialized for d_model == 2048: 2 blocks per token, 1 float4 per thread.
__global__ __launch_bounds__(NT) void combine2048_kernel(
    const float* __restrict__ expert,
    const float* __restrict__ gates,
    const int* __restrict__ counts,
    const int* __restrict__ slots,
    float* __restrict__ out) {
    const int b    = blockIdx.x;
    const int t    = b >> 1;                       // token
    const int col4 = ((b & 1) * NT + threadIdx.x); // float4 index in [0,512)
    int c = counts[t];
    if (c > MAXK) c = MAXK;
    const int* sl = slots + t * MAXK;

    fvec4 acc = (fvec4)(0.f);
    for (int j = 0; j < c; ++j) {
        int   r = sl[j];                 // wave-uniform
        float g = gates[r];              // wave-uniform
        const fvec4* row = (const fvec4*)(expert + (size_t)r * 2048);
        fvec4 e = __builtin_nontemporal_load(row + col4);  // streamed once: nt
        acc.x = fmaf(g, e.x, acc.x);
        acc.y = fmaf(g, e.y, acc.y);
        acc.z = fmaf(g, e.z, acc.z);
        acc.w = fmaf(g, e.w, acc.w);
    }
    fvec4* o = (fvec4*)(out + (size_t)t * 2048);
    __builtin_nontemporal_store(acc, o + col4);  // write-only: nt
}

// Fallback: plain atomic scatter (generic d_model, or ws too small).
__global__ void scatter_atomic_kernel(const float* __restrict__ expert,
                                      const float* __restrict__ gates,
                                      const int* __restrict__ idx32,
                                      const long long* __restrict__ idx64,
                                      float* __restrict__ out,
                                      int d_model, int num_tokens) {
    int r = blockIdx.x;
    int is64 = 1;
#pragma unroll
    for (int i = 1; i < 32; i += 2) is64 &= (idx32[i] == 0);
    int t = is64 ? (int)idx64[r] : idx32[r];
    if ((unsigned)t >= (unsigned)num_tokens) return;
    float g = gates[r];
    const float* row  = expert + (size_t)r * d_model;
    float*       orow = out    + (size_t)t * d_model;
    for (int v = threadIdx.x; v < d_model; v += blockDim.x)
        atomicAdd(&orow[v], g * row[v]);
}

extern "C" void kernel_launch(void* const* d_in, const int* in_sizes, int n_in,
                              void* d_out, int out_size, void* d_ws, size_t ws_size,
                              hipStream_t stream) {
    const float*      expert = (const float*)d_in[1];
    const float*      gates  = (const float*)d_in[2];
    const int*        idx32  = (const int*)d_in[3];
    const long long*  idx64  = (const long long*)d_in[3];
    float*            out    = (float*)d_out;

    const int num_sel    = in_sizes[2];
    const int d_model    = (int)((long long)in_sizes[1] / num_sel);
    const int num_tokens = (int)((long long)out_size / d_model);

    int*  counts = (int*)d_ws;
    int*  slots  = (int*)((char*)d_ws + (size_t)num_tokens * 4);
    const size_t need = (size_t)num_tokens * 4 + (size_t)num_tokens * MAXK * 4;

    if (d_model == 2048 && ws_size >= need) {
        (void)hipMemsetAsync(counts, 0, (size_t)num_tokens * 4, stream);  // ws re-poisoned 0xAA
        fill_kernel<<<(num_sel + NT - 1) / NT, NT, 0, stream>>>(
            idx32, idx64, counts, slots, num_sel, num_tokens);
        combine2048_kernel<<<num_tokens * 2, NT, 0, stream>>>(expert, gates, counts, slots, out);
    } else {
        (void)hipMemsetAsync(d_out, 0, (size_t)out_size * sizeof(float), stream);
        scatter_atomic_kernel<<<num_sel, NT, 0, stream>>>(
            expert, gates, idx32, idx64, out, d_model, num_tokens);
    }
}